// Round 1
// baseline (78.935 us; speedup 1.0000x reference)
//
#include <hip/hip_runtime.h>
#include <hip/hip_bf16.h>

// SWA with sinks: B=2, Q=512, HQ=32, HKV=8 (GQA rep=4), D=128, BS=128,
// NBLK=16, MAXK=2048, WIN=1024 (read dynamically). fp32 in/out, bf16 MFMA.

#define B_    2
#define Q_    512
#define HQ_   32
#define HKV_  8
#define D_    128
#define BS_   128
#define NBLK_ 16
#define QBLK  64
#define KBLK  64
#define KP    136   // K LDS pitch (ushort elements), 272B rows (16B aligned)
#define PP    72    // P LDS pitch, 144B rows
#define KVROW (HKV_*D_)   // 1024 floats per key position

typedef __attribute__((ext_vector_type(8))) __bf16 bf16x8;
typedef __attribute__((ext_vector_type(4))) float  f32x4;
typedef __attribute__((ext_vector_type(4))) float  float4v;
typedef __attribute__((ext_vector_type(4))) unsigned int u32x4;
typedef __attribute__((ext_vector_type(2))) unsigned int u32x2;

__device__ __forceinline__ unsigned f2bf_u(float f) {
    unsigned u = __builtin_bit_cast(unsigned, f);
    return (u + 0x7fffu + ((u >> 16) & 1u)) >> 16;   // RNE, no NaNs in data
}
__device__ __forceinline__ unsigned pk2(float a, float b) {
    return f2bf_u(a) | (f2bf_u(b) << 16);
}

__global__ __launch_bounds__(256, 2) void swa_kernel(
    const float* __restrict__ q,
    const int*   __restrict__ btab,
    const float* __restrict__ kv,
    const int*   __restrict__ seqused,
    const float* __restrict__ sinks,
    const int*   __restrict__ winp,
    float*       __restrict__ out)
{
    __shared__ __align__(16) unsigned short Klds[64 * KP];      // [k][d] row-major
    __shared__ __align__(16) unsigned short Vlds[64 * 128];     // fragment-linear V^T
    __shared__ __align__(16) unsigned short Plds[4][16 * PP];   // per-wave P [q][k]

    const int tid  = threadIdx.x;
    const int lane = tid & 63;
    const int w    = tid >> 6;
    const int l15  = lane & 15;
    const int lhi  = lane >> 4;

    const int bid = blockIdx.x;
    const int qt  = bid & 7;
    const int h   = (bid >> 3) & 31;
    const int b   = bid >> 8;
    const int kh  = h >> 2;          // rep = HQ/HKV = 4

    const int seq  = seqused[b];
    const int win  = winp[0];
    const int q0   = qt * QBLK;
    const int pos0 = seq - Q_ + q0;

    const int lo  = pos0 - win + 1;
    const int jt0 = (lo < 0 ? 0 : lo) & ~63;
    const int jt1 = (pos0 + QBLK - 1) & ~63;

    // ---- Q fragments (16 rows per wave, bf16, kept in registers) ----
    const int    qr    = q0 + w * 16 + l15;
    const size_t qbase = ((size_t)(b * Q_ + qr) * HQ_ + h) * D_;
    bf16x8 qf[4];
    #pragma unroll
    for (int dc = 0; dc < 4; ++dc) {
        const float4v f0 = *reinterpret_cast<const float4v*>(q + qbase + dc * 32 + lhi * 8);
        const float4v f1 = *reinterpret_cast<const float4v*>(q + qbase + dc * 32 + lhi * 8 + 4);
        u32x4 p;
        p[0] = pk2(f0[0], f0[1]); p[1] = pk2(f0[2], f0[3]);
        p[2] = pk2(f1[0], f1[1]); p[3] = pk2(f1[2], f1[3]);
        qf[dc] = __builtin_bit_cast(bf16x8, p);
    }

    const int   posq = pos0 + w * 16 + l15;   // key position of this lane's q row
    const float sink = sinks[h];
    float mrun = sink;       // running max init = sink  => denom sink term free
    float lrun = 1.0f;       // exp(sink - mrun) = 1
    f32x4 o[8];
    #pragma unroll
    for (int g = 0; g < 8; ++g) o[g] = (f32x4){0.f, 0.f, 0.f, 0.f};

    const float scale = 0.08838834764831845f;  // 1/sqrt(128)

    for (int jt = jt0; jt <= jt1; jt += KBLK) {
        const int    blk    = btab[b * NBLK_ + (jt >> 7)];
        const size_t kgbase = (size_t)blk * (2 * BS_ * KVROW) + (size_t)(jt & 127) * KVROW + kh * D_;
        const size_t vgbase = kgbase + (size_t)BS_ * KVROW;

        __syncthreads();   // previous tile fully consumed

        // ---- stage K tile: row kl = tid>>2, 32 d per thread ----
        {
            const int kl = tid >> 2;
            const int d0 = (tid & 3) * 32;
            const float* src = kv + kgbase + (size_t)kl * KVROW + d0;
            #pragma unroll
            for (int i = 0; i < 4; ++i) {
                const float4v f0 = *reinterpret_cast<const float4v*>(src + i * 8);
                const float4v f1 = *reinterpret_cast<const float4v*>(src + i * 8 + 4);
                u32x4 p;
                p[0] = pk2(f0[0], f0[1]); p[1] = pk2(f0[2], f0[3]);
                p[2] = pk2(f1[0], f1[1]); p[3] = pk2(f1[2], f1[3]);
                *reinterpret_cast<u32x4*>(&Klds[kl * KP + d0 + i * 8]) = p;
            }
        }
        // ---- stage V^T (fragment-linear, 4x4 in-register transpose) ----
        {
            const int db = tid & 31;   // d block (4 d's)
            #pragma unroll
            for (int half = 0; half < 2; ++half) {
                const int kb = (tid >> 5) + half * 8;   // k block (4 k's)
                const int k0 = kb * 4;
                const float* vsrc = kv + vgbase + (size_t)k0 * KVROW + db * 4;
                const float4v r0 = *reinterpret_cast<const float4v*>(vsrc);
                const float4v r1 = *reinterpret_cast<const float4v*>(vsrc + KVROW);
                const float4v r2 = *reinterpret_cast<const float4v*>(vsrc + 2 * KVROW);
                const float4v r3 = *reinterpret_cast<const float4v*>(vsrc + 3 * KVROW);
                #pragma unroll
                for (int dd = 0; dd < 4; ++dd) {
                    const int d    = db * 4 + dd;
                    const int g    = d >> 4;
                    const int slot = ((kb >> 1) & 3) * 16 + ((d & 15) ^ (g & 7));
                    const int elem = (g * 2 + (k0 >> 5)) * 512 + slot * 8 + (k0 & 7);
                    u32x2 wv;
                    wv[0] = pk2(r0[dd], r1[dd]);
                    wv[1] = pk2(r2[dd], r3[dd]);
                    *reinterpret_cast<u32x2*>(&Vlds[elem]) = wv;
                }
            }
        }
        __syncthreads();

        // ---- S^T = K · Q  (64k x 16q), 4 row-frags x 4 d-chunks ----
        f32x4 sacc[4];
        #pragma unroll
        for (int g = 0; g < 4; ++g) sacc[g] = (f32x4){0.f, 0.f, 0.f, 0.f};
        #pragma unroll
        for (int g = 0; g < 4; ++g) {
            #pragma unroll
            for (int dc = 0; dc < 4; ++dc) {
                const bf16x8 a = *reinterpret_cast<const bf16x8*>(
                    &Klds[(g * 16 + l15) * KP + dc * 32 + lhi * 8]);
                sacc[g] = __builtin_amdgcn_mfma_f32_16x16x32_bf16(a, qf[dc], sacc[g], 0, 0, 0);
            }
        }

        // ---- masking + online softmax (lane owns q = l15; 16 k values) ----
        float sv[16];
        float mloc = -3e38f;
        #pragma unroll
        for (int g = 0; g < 4; ++g) {
            #pragma unroll
            for (int i = 0; i < 4; ++i) {
                const int  kglob = jt + g * 16 + lhi * 4 + i;
                float s = sacc[g][i] * scale;
                const bool ok = (kglob <= posq) && (kglob > posq - win);
                s = ok ? s : -1e30f;
                sv[g * 4 + i] = s;
                mloc = fmaxf(mloc, s);
            }
        }
        mloc = fmaxf(mloc, __shfl_xor(mloc, 16));
        mloc = fmaxf(mloc, __shfl_xor(mloc, 32));
        const float mnew  = fmaxf(mrun, mloc);
        const float alpha = __expf(mrun - mnew);

        float ps = 0.f;
        unsigned pw[8];
        #pragma unroll
        for (int t = 0; t < 8; ++t) {
            const float p0 = __expf(sv[2 * t]     - mnew);
            const float p1 = __expf(sv[2 * t + 1] - mnew);
            ps += p0 + p1;
            pw[t] = pk2(p0, p1);
        }
        ps += __shfl_xor(ps, 16);
        ps += __shfl_xor(ps, 32);
        lrun = lrun * alpha + ps;
        mrun = mnew;
        #pragma unroll
        for (int g = 0; g < 8; ++g) o[g] *= alpha;

        // ---- write P [q][k] (per-wave private region) ----
        #pragma unroll
        for (int g = 0; g < 4; ++g) {
            u32x2 wv; wv[0] = pw[2 * g]; wv[1] = pw[2 * g + 1];
            *reinterpret_cast<u32x2*>(&Plds[w][l15 * PP + g * 16 + lhi * 4]) = wv;
        }

        // ---- O^T += V^T · P  (8 d-frags x 2 k-chunks) ----
        #pragma unroll
        for (int kc = 0; kc < 2; ++kc) {
            const bf16x8 pf = *reinterpret_cast<const bf16x8*>(
                &Plds[w][l15 * PP + kc * 32 + lhi * 8]);
            #pragma unroll
            for (int g = 0; g < 8; ++g) {
                const bf16x8 vf = *reinterpret_cast<const bf16x8*>(
                    &Vlds[(g * 2 + kc) * 512 + (lhi * 16 + (l15 ^ (g & 7))) * 8]);
                o[g] = __builtin_amdgcn_mfma_f32_16x16x32_bf16(vf, pf, o[g], 0, 0, 0);
            }
        }
    }

    // ---- epilogue: out = O / l ----
    const float  inv   = 1.0f / lrun;
    const size_t obase = ((size_t)(b * Q_ + qr) * HQ_ + h) * D_;
    #pragma unroll
    for (int g = 0; g < 8; ++g) {
        float4v v;
        v[0] = o[g][0] * inv; v[1] = o[g][1] * inv;
        v[2] = o[g][2] * inv; v[3] = o[g][3] * inv;
        *reinterpret_cast<float4v*>(out + obase + g * 16 + lhi * 4) = v;
    }
}

extern "C" void kernel_launch(void* const* d_in, const int* in_sizes, int n_in,
                              void* d_out, int out_size, void* d_ws, size_t ws_size,
                              hipStream_t stream) {
    const float* q       = (const float*)d_in[0];
    const int*   btab    = (const int*)  d_in[1];
    const float* kv      = (const float*)d_in[2];
    const int*   seqused = (const int*)  d_in[3];
    const float* sinks   = (const float*)d_in[4];
    const int*   win     = (const int*)  d_in[5];
    // d_in[6] = mask (all-false in this problem), d_in[7] = cu_seqlens_q (unused by ref)
    float* out = (float*)d_out;

    swa_kernel<<<dim3(B_ * HQ_ * (Q_ / QBLK)), dim3(256), 0, stream>>>(
        q, btab, kv, seqused, sinks, win, out);
}

// Round 2
// 64.267 us; speedup vs baseline: 1.2282x; 1.2282x over previous
//
#include <hip/hip_runtime.h>
#include <hip/hip_bf16.h>

// SWA with sinks: B=2, Q=512, HQ=32, HKV=8 (GQA rep=4), D=128, BS=128,
// NBLK=16, MAXK=2048, WIN=1024 (read dynamically). fp32 in/out, bf16 MFMA.
// R2: K-LDS XOR swizzle (kills 16-way ds_read conflicts), compiler cvt_pk
// bf16 packing, exp2-domain softmax (scale*log2e folded into Q), T13
// defer-rescale, edge/interior tile split, fully-masked-tile wave skip.

#define B_    2
#define Q_    512
#define HQ_   32
#define HKV_  8
#define D_    128
#define BS_   128
#define NBLK_ 16
#define QBLK  64
#define KBLK  64
#define PP    72    // P LDS pitch (ushort), 144B rows -> 2-way (free) conflicts
#define KVROW (HKV_*D_)   // 1024 floats per key position

typedef __attribute__((ext_vector_type(8))) __bf16 bf16x8;
typedef __attribute__((ext_vector_type(4))) float  f32x4;
typedef __attribute__((ext_vector_type(4))) float  float4v;
typedef __attribute__((ext_vector_type(4))) unsigned int u32x4;
typedef __attribute__((ext_vector_type(2))) unsigned int u32x2;

#if __has_builtin(__builtin_amdgcn_exp2f)
#define EXP2(x) __builtin_amdgcn_exp2f(x)
#else
#define EXP2(x) exp2f(x)
#endif

// Compiler emits v_cvt_pk_bf16_f32 from paired scalar casts (m240).
__device__ __forceinline__ unsigned pk2(float a, float b) {
    union { __bf16 h[2]; unsigned u; } x;
    x.h[0] = (__bf16)a; x.h[1] = (__bf16)b;
    return x.u;
}

__global__ __launch_bounds__(256, 2) void swa_kernel(
    const float* __restrict__ q,
    const int*   __restrict__ btab,
    const float* __restrict__ kv,
    const int*   __restrict__ seqused,
    const float* __restrict__ sinks,
    const int*   __restrict__ winp,
    float*       __restrict__ out)
{
    __shared__ __align__(16) unsigned short Klds[64 * 128];   // [k][d], XOR-swizzled
    __shared__ __align__(16) unsigned short Vlds[64 * 128];   // fragment-linear V^T
    __shared__ __align__(16) unsigned short Plds[4][16 * PP]; // per-wave P [q][k]

    const int tid  = threadIdx.x;
    const int lane = tid & 63;
    const int w    = tid >> 6;
    const int l15  = lane & 15;
    const int lhi  = lane >> 4;

    const int bid = blockIdx.x;
    const int qt  = bid & 7;
    const int h   = (bid >> 3) & 31;
    const int b   = bid >> 8;
    const int kh  = h >> 2;          // rep = HQ/HKV = 4

    const int seq  = seqused[b];
    const int win  = winp[0];
    const int q0   = qt * QBLK;
    const int pos0 = seq - Q_ + q0;

    const int lo  = pos0 - win + 1;
    const int jt0 = (lo < 0 ? 0 : lo) & ~63;
    const int jt1 = (pos0 + QBLK - 1) & ~63;

    // log2-domain scale folded into Q once: s2 = (q.k)*scale*log2e
    const float SCL2 = 0.08838834764831845f * 1.4426950408889634f;

    // ---- Q fragments (16 rows per wave, bf16, kept in registers) ----
    const int    qr    = q0 + w * 16 + l15;
    const size_t qbase = ((size_t)(b * Q_ + qr) * HQ_ + h) * D_;
    bf16x8 qf[4];
    #pragma unroll
    for (int dc = 0; dc < 4; ++dc) {
        const float4v f0 = *reinterpret_cast<const float4v*>(q + qbase + dc * 32 + lhi * 8);
        const float4v f1 = *reinterpret_cast<const float4v*>(q + qbase + dc * 32 + lhi * 8 + 4);
        u32x4 p;
        p[0] = pk2(f0[0] * SCL2, f0[1] * SCL2); p[1] = pk2(f0[2] * SCL2, f0[3] * SCL2);
        p[2] = pk2(f1[0] * SCL2, f1[1] * SCL2); p[3] = pk2(f1[2] * SCL2, f1[3] * SCL2);
        qf[dc] = __builtin_bit_cast(bf16x8, p);
    }

    const int   pqmin = pos0 + w * 16;        // this wave's lowest q position
    const int   pqmax = pqmin + 15;
    const int   posq  = pqmin + l15;          // this lane's q position
    const float sink2 = sinks[h] * 1.4426950408889634f;
    float mrun = sink2;      // running max (log2 units) init = sink
    float lrun = 1.0f;       // 2^(sink2 - mrun) = 1  => sink denom term free
    f32x4 o[8];
    #pragma unroll
    for (int g = 0; g < 8; ++g) o[g] = (f32x4){0.f, 0.f, 0.f, 0.f};

    for (int jt = jt0; jt <= jt1; jt += KBLK) {
        const int    blk    = btab[b * NBLK_ + (jt >> 7)];
        const size_t kgbase = (size_t)blk * (2 * BS_ * KVROW) + (size_t)(jt & 127) * KVROW + kh * D_;
        const size_t vgbase = kgbase + (size_t)BS_ * KVROW;

        __syncthreads();   // previous tile fully consumed

        // ---- stage K tile: row kl = tid>>2, 32 d per thread, XOR-swizzled ----
        {
            const int kl = tid >> 2;
            const int cb = (tid & 3) * 64;   // column byte base
            const float* src = kv + kgbase + (size_t)kl * KVROW + (tid & 3) * 32;
            char* dst = (char*)Klds + kl * 256;
            #pragma unroll
            for (int i = 0; i < 4; ++i) {
                const float4v f0 = *reinterpret_cast<const float4v*>(src + i * 8);
                const float4v f1 = *reinterpret_cast<const float4v*>(src + i * 8 + 4);
                u32x4 p;
                p[0] = pk2(f0[0], f0[1]); p[1] = pk2(f0[2], f0[3]);
                p[2] = pk2(f1[0], f1[1]); p[3] = pk2(f1[2], f1[3]);
                *reinterpret_cast<u32x4*>(dst + ((cb + i * 16) ^ ((kl & 15) << 4))) = p;
            }
        }
        // ---- stage V^T (fragment-linear, 4x4 in-register transpose) ----
        {
            const int db = tid & 31;   // d block (4 d's)
            #pragma unroll
            for (int half = 0; half < 2; ++half) {
                const int kb = (tid >> 5) + half * 8;   // k block (4 k's)
                const int k0 = kb * 4;
                const float* vsrc = kv + vgbase + (size_t)k0 * KVROW + db * 4;
                const float4v r0 = *reinterpret_cast<const float4v*>(vsrc);
                const float4v r1 = *reinterpret_cast<const float4v*>(vsrc + KVROW);
                const float4v r2 = *reinterpret_cast<const float4v*>(vsrc + 2 * KVROW);
                const float4v r3 = *reinterpret_cast<const float4v*>(vsrc + 3 * KVROW);
                #pragma unroll
                for (int dd = 0; dd < 4; ++dd) {
                    const int d    = db * 4 + dd;
                    const int g    = d >> 4;
                    const int slot = ((kb >> 1) & 3) * 16 + ((d & 15) ^ (g & 7));
                    const int elem = (g * 2 + (k0 >> 5)) * 512 + slot * 8 + (k0 & 7);
                    u32x2 wv;
                    wv[0] = pk2(r0[dd], r1[dd]);
                    wv[1] = pk2(r2[dd], r3[dd]);
                    *reinterpret_cast<u32x2*>(&Vlds[elem]) = wv;
                }
            }
        }
        __syncthreads();

        // wave-level skip: tile fully masked for all 16 rows of this wave
        if (jt > pqmax || jt + KBLK - 1 <= pqmin - win) continue;
        const bool edge = (jt + KBLK - 1 > pqmin) || (jt <= pqmax - win);

        // ---- S^T = K · Q  (64k x 16q), 4 row-frags x 4 d-chunks ----
        f32x4 sacc[4];
        #pragma unroll
        for (int g = 0; g < 4; ++g) sacc[g] = (f32x4){0.f, 0.f, 0.f, 0.f};
        #pragma unroll
        for (int g = 0; g < 4; ++g) {
            const char* krow = (const char*)Klds + (g * 16 + l15) * 256;
            const int   swz  = (l15 << 4);
            #pragma unroll
            for (int dc = 0; dc < 4; ++dc) {
                const bf16x8 a = *reinterpret_cast<const bf16x8*>(
                    krow + ((dc * 64 + lhi * 16) ^ swz));
                sacc[g] = __builtin_amdgcn_mfma_f32_16x16x32_bf16(a, qf[dc], sacc[g], 0, 0, 0);
            }
        }

        // ---- masking + online softmax (lane owns q = l15; 16 k values) ----
        float sv[16];
        float mloc = -3e38f;
        if (edge) {
            #pragma unroll
            for (int g = 0; g < 4; ++g) {
                #pragma unroll
                for (int i = 0; i < 4; ++i) {
                    const int  kglob = jt + g * 16 + lhi * 4 + i;
                    const bool ok = (kglob <= posq) && (kglob > posq - win);
                    const float s = ok ? sacc[g][i] : -1e30f;
                    sv[g * 4 + i] = s;
                    mloc = fmaxf(mloc, s);
                }
            }
        } else {
            #pragma unroll
            for (int g = 0; g < 4; ++g) {
                #pragma unroll
                for (int i = 0; i < 4; ++i) {
                    sv[g * 4 + i] = sacc[g][i];
                    mloc = fmaxf(mloc, sacc[g][i]);
                }
            }
        }
        mloc = fmaxf(mloc, __shfl_xor(mloc, 16));
        mloc = fmaxf(mloc, __shfl_xor(mloc, 32));

        // T13 defer-rescale: only rescale when max grew by > 8 (P <= 2^8, bf16-safe)
        if (!__all(mloc <= mrun + 8.0f)) {
            const float mnew  = fmaxf(mrun, mloc);
            const float alpha = EXP2(mrun - mnew);
            lrun *= alpha;
            #pragma unroll
            for (int g = 0; g < 8; ++g) o[g] *= alpha;
            mrun = mnew;
        }

        float ps = 0.f;
        unsigned pw[8];
        #pragma unroll
        for (int t = 0; t < 8; ++t) {
            const float p0 = EXP2(sv[2 * t]     - mrun);
            const float p1 = EXP2(sv[2 * t + 1] - mrun);
            ps += p0 + p1;
            pw[t] = pk2(p0, p1);
        }
        ps += __shfl_xor(ps, 16);
        ps += __shfl_xor(ps, 32);
        lrun += ps;

        // ---- write P [q][k] (per-wave private region) ----
        #pragma unroll
        for (int g = 0; g < 4; ++g) {
            u32x2 wv; wv[0] = pw[2 * g]; wv[1] = pw[2 * g + 1];
            *reinterpret_cast<u32x2*>(&Plds[w][l15 * PP + g * 16 + lhi * 4]) = wv;
        }

        // ---- O^T += V^T · P  (8 d-frags x 2 k-chunks) ----
        #pragma unroll
        for (int kc = 0; kc < 2; ++kc) {
            const bf16x8 pf = *reinterpret_cast<const bf16x8*>(
                &Plds[w][l15 * PP + kc * 32 + lhi * 8]);
            #pragma unroll
            for (int g = 0; g < 8; ++g) {
                const bf16x8 vf = *reinterpret_cast<const bf16x8*>(
                    &Vlds[(g * 2 + kc) * 512 + (lhi * 16 + (l15 ^ (g & 7))) * 8]);
                o[g] = __builtin_amdgcn_mfma_f32_16x16x32_bf16(vf, pf, o[g], 0, 0, 0);
            }
        }
    }

    // ---- epilogue: out = O / l ----
    const float  inv   = 1.0f / lrun;
    const size_t obase = ((size_t)(b * Q_ + qr) * HQ_ + h) * D_;
    #pragma unroll
    for (int g = 0; g < 8; ++g) {
        float4v v;
        v[0] = o[g][0] * inv; v[1] = o[g][1] * inv;
        v[2] = o[g][2] * inv; v[3] = o[g][3] * inv;
        *reinterpret_cast<float4v*>(out + obase + g * 16 + lhi * 4) = v;
    }
}

extern "C" void kernel_launch(void* const* d_in, const int* in_sizes, int n_in,
                              void* d_out, int out_size, void* d_ws, size_t ws_size,
                              hipStream_t stream) {
    const float* q       = (const float*)d_in[0];
    const int*   btab    = (const int*)  d_in[1];
    const float* kv      = (const float*)d_in[2];
    const int*   seqused = (const int*)  d_in[3];
    const float* sinks   = (const float*)d_in[4];
    const int*   win     = (const int*)  d_in[5];
    // d_in[6] = mask (all-false in this problem), d_in[7] = cu_seqlens_q (unused by ref)
    float* out = (float*)d_out;

    swa_kernel<<<dim3(B_ * HQ_ * (Q_ / QBLK)), dim3(256), 0, stream>>>(
        q, btab, kv, seqused, sinks, win, out);
}

// Round 3
// 55.859 us; speedup vs baseline: 1.4131x; 1.1505x over previous
//
#include <hip/hip_runtime.h>
#include <hip/hip_bf16.h>

// SWA with sinks: B=2, Q=512, HQ=32, HKV=8 (GQA rep=4), D=128, BS=128,
// NBLK=16, MAXK=2048, WIN=1024 (read dynamically). fp32 in/out, bf16 MFMA.
// R3: pre-pass converts KV fp32->bf16 into d_ws ONCE (K XOR-swizzled rows,
// V fragment-linear transposed), main kernel stages via global_load_lds
// (width 16) with depth-1 prefetch double-buffer (T3 2-phase minimum).
// Fallback to R2-style kernel if ws_size too small.

#define B_    2
#define Q_    512
#define HQ_   32
#define HKV_  8
#define D_    128
#define BS_   128
#define NBLK_ 16
#define NPHYS (B_*NBLK_)
#define QBLK  64
#define KBLK  64
#define PP    72    // P LDS pitch (ushort), 144B rows
#define KVROW (HKV_*D_)   // 1024 floats per key position

typedef __attribute__((ext_vector_type(8))) __bf16 bf16x8;
typedef __attribute__((ext_vector_type(4))) float  f32x4;
typedef __attribute__((ext_vector_type(4))) float  float4v;
typedef __attribute__((ext_vector_type(4))) unsigned int u32x4;
typedef __attribute__((ext_vector_type(2))) unsigned int u32x2;

#if __has_builtin(__builtin_amdgcn_exp2f)
#define EXP2(x) __builtin_amdgcn_exp2f(x)
#else
#define EXP2(x) exp2f(x)
#endif

// Compiler emits v_cvt_pk_bf16_f32 from paired scalar casts (m240).
__device__ __forceinline__ unsigned pk2(float a, float b) {
    union { __bf16 h[2]; unsigned u; } x;
    x.h[0] = (__bf16)a; x.h[1] = (__bf16)b;
    return x.u;
}

__device__ __forceinline__ void gld16(const void* g, void* l) {
    __builtin_amdgcn_global_load_lds(
        (const __attribute__((address_space(1))) void*)g,
        (__attribute__((address_space(3))) void*)l, 16, 0, 0);
}

// ---------------- pre-pass: fp32 KV -> bf16 ws, relayout ----------------
// wsK: [phys][kh][key 128][d 128] bf16, each 256B row XOR-swizzled by
//      byte ^= (key&15)<<4 (so linear LDS staging + swizzled ds_read works).
// wsV: [phys][kh][tile 2][8192] bf16 fragment-linear:
//      elem(k,d) = ((d>>4)*2+(k>>5))*512 + (((k>>3)&3)*16 + ((d&15)^((d>>4)&7)))*8 + (k&7)
__global__ __launch_bounds__(256) void swa_prepass(
    const float* __restrict__ kv,
    unsigned short* __restrict__ wsK,
    unsigned short* __restrict__ wsV)
{
    const int tid  = threadIdx.x;
    const int pk   = blockIdx.x >> 1;     // phys*8 + kh
    const int part = blockIdx.x & 1;
    const int phys = pk >> 3;
    const int kh   = pk & 7;

    if (part == 0) {
        // K: 128 rows x 128 d. thread -> row = tid>>1, d-half = (tid&1)*64
        const int row = tid >> 1;
        const int dh  = (tid & 1) * 64;
        const float* src = kv + ((size_t)(phys * 2 + 0) * BS_ + row) * KVROW + kh * D_ + dh;
        char* dstrow = (char*)(wsK + ((size_t)pk * BS_ + row) * D_);
        const int swz = (row & 15) << 4;
        #pragma unroll
        for (int i = 0; i < 8; ++i) {
            const float4v f0 = *reinterpret_cast<const float4v*>(src + i * 8);
            const float4v f1 = *reinterpret_cast<const float4v*>(src + i * 8 + 4);
            u32x4 p;
            p[0] = pk2(f0[0], f0[1]); p[1] = pk2(f0[2], f0[3]);
            p[2] = pk2(f1[0], f1[1]); p[3] = pk2(f1[2], f1[3]);
            *reinterpret_cast<u32x4*>(dstrow + ((dh * 2 + i * 16) ^ swz)) = p;
        }
    } else {
        // V: 2 tiles x 64 k x 128 d, 4x4 in-register transpose
        const int db  = tid & 31;    // d block of 4
        const int kb8 = tid >> 5;    // 0..7
        #pragma unroll
        for (int tile = 0; tile < 2; ++tile) {
            unsigned short* dstt = wsV + ((size_t)pk * 2 + tile) * 8192;
            #pragma unroll
            for (int half = 0; half < 2; ++half) {
                const int kb  = kb8 + half * 8;   // 0..15
                const int k0  = kb * 4;           // within tile
                const int key = tile * 64 + k0;
                const float* vsrc = kv + ((size_t)(phys * 2 + 1) * BS_ + key) * KVROW + kh * D_ + db * 4;
                const float4v r0 = *reinterpret_cast<const float4v*>(vsrc);
                const float4v r1 = *reinterpret_cast<const float4v*>(vsrc + KVROW);
                const float4v r2 = *reinterpret_cast<const float4v*>(vsrc + 2 * KVROW);
                const float4v r3 = *reinterpret_cast<const float4v*>(vsrc + 3 * KVROW);
                #pragma unroll
                for (int dd = 0; dd < 4; ++dd) {
                    const int d    = db * 4 + dd;
                    const int g    = d >> 4;
                    const int slot = ((kb >> 1) & 3) * 16 + ((d & 15) ^ (g & 7));
                    const int elem = (g * 2 + (k0 >> 5)) * 512 + slot * 8 + (k0 & 7);
                    u32x2 wv;
                    wv[0] = pk2(r0[dd], r1[dd]);
                    wv[1] = pk2(r2[dd], r3[dd]);
                    *reinterpret_cast<u32x2*>(dstt + elem) = wv;
                }
            }
        }
    }
}

// ---------------- main kernel ----------------
__global__ __launch_bounds__(256, 2) void swa_main(
    const float* __restrict__ q,
    const int*   __restrict__ btab,
    const int*   __restrict__ seqused,
    const float* __restrict__ sinks,
    const int*   __restrict__ winp,
    const unsigned short* __restrict__ wsK,
    const unsigned short* __restrict__ wsV,
    float*       __restrict__ out)
{
    __shared__ __align__(16) unsigned short Kb[2][8192];
    __shared__ __align__(16) unsigned short Vb[2][8192];
    __shared__ __align__(16) unsigned short Pl[4][16 * PP];

    const int tid  = threadIdx.x;
    const int lane = tid & 63;
    const int w    = tid >> 6;
    const int l15  = lane & 15;
    const int lhi  = lane >> 4;

    const int bid = blockIdx.x;
    const int qt  = bid & 7;
    const int h   = (bid >> 3) & 31;
    const int b   = bid >> 8;
    const int kh  = h >> 2;

    const int seq  = seqused[b];
    const int win  = winp[0];
    const int q0   = qt * QBLK;
    const int pos0 = seq - Q_ + q0;

    const int lo  = pos0 - win + 1;
    const int jt0 = (lo < 0 ? 0 : lo) & ~63;
    const int jt1 = (pos0 + QBLK - 1) & ~63;
    const int nt  = ((jt1 - jt0) >> 6) + 1;

    const float SCL2 = 0.08838834764831845f * 1.4426950408889634f;

    // ---- Q fragments ----
    const int    qr    = q0 + w * 16 + l15;
    const size_t qbase = ((size_t)(b * Q_ + qr) * HQ_ + h) * D_;
    bf16x8 qf[4];
    #pragma unroll
    for (int dc = 0; dc < 4; ++dc) {
        const float4v f0 = *reinterpret_cast<const float4v*>(q + qbase + dc * 32 + lhi * 8);
        const float4v f1 = *reinterpret_cast<const float4v*>(q + qbase + dc * 32 + lhi * 8 + 4);
        u32x4 p;
        p[0] = pk2(f0[0] * SCL2, f0[1] * SCL2); p[1] = pk2(f0[2] * SCL2, f0[3] * SCL2);
        p[2] = pk2(f1[0] * SCL2, f1[1] * SCL2); p[3] = pk2(f1[2] * SCL2, f1[3] * SCL2);
        qf[dc] = __builtin_bit_cast(bf16x8, p);
    }

    const int   pqmin = pos0 + w * 16;
    const int   pqmax = pqmin + 15;
    const int   posq  = pqmin + l15;
    const float sink2 = sinks[h] * 1.4426950408889634f;
    float mrun = sink2;
    float lrun = 1.0f;
    f32x4 o[8];
    #pragma unroll
    for (int g = 0; g < 8; ++g) o[g] = (f32x4){0.f, 0.f, 0.f, 0.f};

    // ---- stage tile 0 ----
    {
        const int blk = btab[b * NBLK_ + (jt0 >> 7)];
        const unsigned short* ks = wsK + ((size_t)(blk * 8 + kh) * BS_ + (jt0 & 127)) * D_;
        const unsigned short* vs = wsV + ((size_t)(blk * 8 + kh) * 2 + ((jt0 >> 6) & 1)) * 8192;
        #pragma unroll
        for (int i = 0; i < 4; ++i)
            gld16(ks + (w * 4 + i) * 512 + lane * 8, &Kb[0][(w * 4 + i) * 512]);
        #pragma unroll
        for (int i = 0; i < 4; ++i)
            gld16(vs + (w * 4 + i) * 512 + lane * 8, &Vb[0][(w * 4 + i) * 512]);
    }
    __syncthreads();

    int cur = 0;
    for (int t = 0; t < nt; ++t) {
        const int jt = jt0 + t * KBLK;

        // ---- prefetch next tile into other buffer ----
        if (t + 1 < nt) {
            const int jn  = jt + KBLK;
            const int blk = btab[b * NBLK_ + (jn >> 7)];
            const unsigned short* ks = wsK + ((size_t)(blk * 8 + kh) * BS_ + (jn & 127)) * D_;
            const unsigned short* vs = wsV + ((size_t)(blk * 8 + kh) * 2 + ((jn >> 6) & 1)) * 8192;
            const int nb = cur ^ 1;
            #pragma unroll
            for (int i = 0; i < 4; ++i)
                gld16(ks + (w * 4 + i) * 512 + lane * 8, &Kb[nb][(w * 4 + i) * 512]);
            #pragma unroll
            for (int i = 0; i < 4; ++i)
                gld16(vs + (w * 4 + i) * 512 + lane * 8, &Vb[nb][(w * 4 + i) * 512]);
        }

        // ---- compute (skip if fully masked for this wave) ----
        if (jt <= pqmax && jt + KBLK - 1 > pqmin - win) {
            const bool edge = (jt + KBLK - 1 > pqmin) || (jt <= pqmax - win);

            f32x4 sacc[4];
            #pragma unroll
            for (int g = 0; g < 4; ++g) sacc[g] = (f32x4){0.f, 0.f, 0.f, 0.f};
            #pragma unroll
            for (int g = 0; g < 4; ++g) {
                const char* krow = (const char*)&Kb[cur][0] + (g * 16 + l15) * 256;
                const int   swz  = (l15 << 4);
                #pragma unroll
                for (int dc = 0; dc < 4; ++dc) {
                    const bf16x8 a = *reinterpret_cast<const bf16x8*>(
                        krow + ((dc * 64 + lhi * 16) ^ swz));
                    sacc[g] = __builtin_amdgcn_mfma_f32_16x16x32_bf16(a, qf[dc], sacc[g], 0, 0, 0);
                }
            }

            float sv[16];
            float mloc = -3e38f;
            if (edge) {
                #pragma unroll
                for (int g = 0; g < 4; ++g) {
                    #pragma unroll
                    for (int i = 0; i < 4; ++i) {
                        const int  kglob = jt + g * 16 + lhi * 4 + i;
                        const bool ok = (kglob <= posq) && (kglob > posq - win);
                        const float s = ok ? sacc[g][i] : -1e30f;
                        sv[g * 4 + i] = s;
                        mloc = fmaxf(mloc, s);
                    }
                }
            } else {
                #pragma unroll
                for (int g = 0; g < 4; ++g) {
                    #pragma unroll
                    for (int i = 0; i < 4; ++i) {
                        sv[g * 4 + i] = sacc[g][i];
                        mloc = fmaxf(mloc, sacc[g][i]);
                    }
                }
            }
            mloc = fmaxf(mloc, __shfl_xor(mloc, 16));
            mloc = fmaxf(mloc, __shfl_xor(mloc, 32));

            if (!__all(mloc <= mrun + 8.0f)) {
                const float mnew  = fmaxf(mrun, mloc);
                const float alpha = EXP2(mrun - mnew);
                lrun *= alpha;
                #pragma unroll
                for (int g = 0; g < 8; ++g) o[g] *= alpha;
                mrun = mnew;
            }

            float ps = 0.f;
            unsigned pw[8];
            #pragma unroll
            for (int t2 = 0; t2 < 8; ++t2) {
                const float p0 = EXP2(sv[2 * t2]     - mrun);
                const float p1 = EXP2(sv[2 * t2 + 1] - mrun);
                ps += p0 + p1;
                pw[t2] = pk2(p0, p1);
            }
            ps += __shfl_xor(ps, 16);
            ps += __shfl_xor(ps, 32);
            lrun += ps;

            #pragma unroll
            for (int g = 0; g < 4; ++g) {
                u32x2 wv; wv[0] = pw[2 * g]; wv[1] = pw[2 * g + 1];
                *reinterpret_cast<u32x2*>(&Pl[w][l15 * PP + g * 16 + lhi * 4]) = wv;
            }

            #pragma unroll
            for (int kc = 0; kc < 2; ++kc) {
                const bf16x8 pf = *reinterpret_cast<const bf16x8*>(
                    &Pl[w][l15 * PP + kc * 32 + lhi * 8]);
                #pragma unroll
                for (int g = 0; g < 8; ++g) {
                    const bf16x8 vf = *reinterpret_cast<const bf16x8*>(
                        &Vb[cur][(g * 2 + kc) * 512 + (lhi * 16 + (l15 ^ (g & 7))) * 8]);
                    o[g] = __builtin_amdgcn_mfma_f32_16x16x32_bf16(vf, pf, o[g], 0, 0, 0);
                }
            }
        }

        __syncthreads();   // drains vmcnt (prefetch done) + protects buffers
        cur ^= 1;
    }

    const float  inv   = 1.0f / lrun;
    const size_t obase = ((size_t)(b * Q_ + qr) * HQ_ + h) * D_;
    #pragma unroll
    for (int g = 0; g < 8; ++g) {
        float4v v;
        v[0] = o[g][0] * inv; v[1] = o[g][1] * inv;
        v[2] = o[g][2] * inv; v[3] = o[g][3] * inv;
        *reinterpret_cast<float4v*>(out + obase + g * 16 + lhi * 4) = v;
    }
}

// ---------------- fallback (R2 kernel, used if ws too small) ----------------
__global__ __launch_bounds__(256, 2) void swa_fallback(
    const float* __restrict__ q,
    const int*   __restrict__ btab,
    const float* __restrict__ kv,
    const int*   __restrict__ seqused,
    const float* __restrict__ sinks,
    const int*   __restrict__ winp,
    float*       __restrict__ out)
{
    __shared__ __align__(16) unsigned short Klds[64 * 128];
    __shared__ __align__(16) unsigned short Vlds[64 * 128];
    __shared__ __align__(16) unsigned short Plds[4][16 * PP];

    const int tid  = threadIdx.x;
    const int lane = tid & 63;
    const int w    = tid >> 6;
    const int l15  = lane & 15;
    const int lhi  = lane >> 4;

    const int bid = blockIdx.x;
    const int qt  = bid & 7;
    const int h   = (bid >> 3) & 31;
    const int b   = bid >> 8;
    const int kh  = h >> 2;

    const int seq  = seqused[b];
    const int win  = winp[0];
    const int q0   = qt * QBLK;
    const int pos0 = seq - Q_ + q0;

    const int lo  = pos0 - win + 1;
    const int jt0 = (lo < 0 ? 0 : lo) & ~63;
    const int jt1 = (pos0 + QBLK - 1) & ~63;

    const float SCL2 = 0.08838834764831845f * 1.4426950408889634f;

    const int    qr    = q0 + w * 16 + l15;
    const size_t qbase = ((size_t)(b * Q_ + qr) * HQ_ + h) * D_;
    bf16x8 qf[4];
    #pragma unroll
    for (int dc = 0; dc < 4; ++dc) {
        const float4v f0 = *reinterpret_cast<const float4v*>(q + qbase + dc * 32 + lhi * 8);
        const float4v f1 = *reinterpret_cast<const float4v*>(q + qbase + dc * 32 + lhi * 8 + 4);
        u32x4 p;
        p[0] = pk2(f0[0] * SCL2, f0[1] * SCL2); p[1] = pk2(f0[2] * SCL2, f0[3] * SCL2);
        p[2] = pk2(f1[0] * SCL2, f1[1] * SCL2); p[3] = pk2(f1[2] * SCL2, f1[3] * SCL2);
        qf[dc] = __builtin_bit_cast(bf16x8, p);
    }

    const int   pqmin = pos0 + w * 16;
    const int   pqmax = pqmin + 15;
    const int   posq  = pqmin + l15;
    const float sink2 = sinks[h] * 1.4426950408889634f;
    float mrun = sink2;
    float lrun = 1.0f;
    f32x4 o[8];
    #pragma unroll
    for (int g = 0; g < 8; ++g) o[g] = (f32x4){0.f, 0.f, 0.f, 0.f};

    for (int jt = jt0; jt <= jt1; jt += KBLK) {
        const int    blk    = btab[b * NBLK_ + (jt >> 7)];
        const size_t kgbase = (size_t)blk * (2 * BS_ * KVROW) + (size_t)(jt & 127) * KVROW + kh * D_;
        const size_t vgbase = kgbase + (size_t)BS_ * KVROW;

        __syncthreads();
        {
            const int kl = tid >> 2;
            const int cb = (tid & 3) * 64;
            const float* src = kv + kgbase + (size_t)kl * KVROW + (tid & 3) * 32;
            char* dst = (char*)Klds + kl * 256;
            #pragma unroll
            for (int i = 0; i < 4; ++i) {
                const float4v f0 = *reinterpret_cast<const float4v*>(src + i * 8);
                const float4v f1 = *reinterpret_cast<const float4v*>(src + i * 8 + 4);
                u32x4 p;
                p[0] = pk2(f0[0], f0[1]); p[1] = pk2(f0[2], f0[3]);
                p[2] = pk2(f1[0], f1[1]); p[3] = pk2(f1[2], f1[3]);
                *reinterpret_cast<u32x4*>(dst + ((cb + i * 16) ^ ((kl & 15) << 4))) = p;
            }
        }
        {
            const int db = tid & 31;
            #pragma unroll
            for (int half = 0; half < 2; ++half) {
                const int kb = (tid >> 5) + half * 8;
                const int k0 = kb * 4;
                const float* vsrc = kv + vgbase + (size_t)k0 * KVROW + db * 4;
                const float4v r0 = *reinterpret_cast<const float4v*>(vsrc);
                const float4v r1 = *reinterpret_cast<const float4v*>(vsrc + KVROW);
                const float4v r2 = *reinterpret_cast<const float4v*>(vsrc + 2 * KVROW);
                const float4v r3 = *reinterpret_cast<const float4v*>(vsrc + 3 * KVROW);
                #pragma unroll
                for (int dd = 0; dd < 4; ++dd) {
                    const int d    = db * 4 + dd;
                    const int g    = d >> 4;
                    const int slot = ((kb >> 1) & 3) * 16 + ((d & 15) ^ (g & 7));
                    const int elem = (g * 2 + (k0 >> 5)) * 512 + slot * 8 + (k0 & 7);
                    u32x2 wv;
                    wv[0] = pk2(r0[dd], r1[dd]);
                    wv[1] = pk2(r2[dd], r3[dd]);
                    *reinterpret_cast<u32x2*>(&Vlds[elem]) = wv;
                }
            }
        }
        __syncthreads();

        if (jt > pqmax || jt + KBLK - 1 <= pqmin - win) continue;
        const bool edge = (jt + KBLK - 1 > pqmin) || (jt <= pqmax - win);

        f32x4 sacc[4];
        #pragma unroll
        for (int g = 0; g < 4; ++g) sacc[g] = (f32x4){0.f, 0.f, 0.f, 0.f};
        #pragma unroll
        for (int g = 0; g < 4; ++g) {
            const char* krow = (const char*)Klds + (g * 16 + l15) * 256;
            const int   swz  = (l15 << 4);
            #pragma unroll
            for (int dc = 0; dc < 4; ++dc) {
                const bf16x8 a = *reinterpret_cast<const bf16x8*>(
                    krow + ((dc * 64 + lhi * 16) ^ swz));
                sacc[g] = __builtin_amdgcn_mfma_f32_16x16x32_bf16(a, qf[dc], sacc[g], 0, 0, 0);
            }
        }

        float sv[16];
        float mloc = -3e38f;
        if (edge) {
            #pragma unroll
            for (int g = 0; g < 4; ++g) {
                #pragma unroll
                for (int i = 0; i < 4; ++i) {
                    const int  kglob = jt + g * 16 + lhi * 4 + i;
                    const bool ok = (kglob <= posq) && (kglob > posq - win);
                    const float s = ok ? sacc[g][i] : -1e30f;
                    sv[g * 4 + i] = s;
                    mloc = fmaxf(mloc, s);
                }
            }
        } else {
            #pragma unroll
            for (int g = 0; g < 4; ++g) {
                #pragma unroll
                for (int i = 0; i < 4; ++i) {
                    sv[g * 4 + i] = sacc[g][i];
                    mloc = fmaxf(mloc, sacc[g][i]);
                }
            }
        }
        mloc = fmaxf(mloc, __shfl_xor(mloc, 16));
        mloc = fmaxf(mloc, __shfl_xor(mloc, 32));

        if (!__all(mloc <= mrun + 8.0f)) {
            const float mnew  = fmaxf(mrun, mloc);
            const float alpha = EXP2(mrun - mnew);
            lrun *= alpha;
            #pragma unroll
            for (int g = 0; g < 8; ++g) o[g] *= alpha;
            mrun = mnew;
        }

        float ps = 0.f;
        unsigned pw[8];
        #pragma unroll
        for (int t = 0; t < 8; ++t) {
            const float p0 = EXP2(sv[2 * t]     - mrun);
            const float p1 = EXP2(sv[2 * t + 1] - mrun);
            ps += p0 + p1;
            pw[t] = pk2(p0, p1);
        }
        ps += __shfl_xor(ps, 16);
        ps += __shfl_xor(ps, 32);
        lrun += ps;

        #pragma unroll
        for (int g = 0; g < 4; ++g) {
            u32x2 wv; wv[0] = pw[2 * g]; wv[1] = pw[2 * g + 1];
            *reinterpret_cast<u32x2*>(&Plds[w][l15 * PP + g * 16 + lhi * 4]) = wv;
        }

        #pragma unroll
        for (int kc = 0; kc < 2; ++kc) {
            const bf16x8 pf = *reinterpret_cast<const bf16x8*>(
                &Plds[w][l15 * PP + kc * 32 + lhi * 8]);
            #pragma unroll
            for (int g = 0; g < 8; ++g) {
                const bf16x8 vf = *reinterpret_cast<const bf16x8*>(
                    &Vlds[(g * 2 + kc) * 512 + (lhi * 16 + (l15 ^ (g & 7))) * 8]);
                o[g] = __builtin_amdgcn_mfma_f32_16x16x32_bf16(vf, pf, o[g], 0, 0, 0);
            }
        }
    }

    const float  inv   = 1.0f / lrun;
    const size_t obase = ((size_t)(b * Q_ + qr) * HQ_ + h) * D_;
    #pragma unroll
    for (int g = 0; g < 8; ++g) {
        float4v v;
        v[0] = o[g][0] * inv; v[1] = o[g][1] * inv;
        v[2] = o[g][2] * inv; v[3] = o[g][3] * inv;
        *reinterpret_cast<float4v*>(out + obase + g * 16 + lhi * 4) = v;
    }
}

extern "C" void kernel_launch(void* const* d_in, const int* in_sizes, int n_in,
                              void* d_out, int out_size, void* d_ws, size_t ws_size,
                              hipStream_t stream) {
    const float* q       = (const float*)d_in[0];
    const int*   btab    = (const int*)  d_in[1];
    const float* kv      = (const float*)d_in[2];
    const int*   seqused = (const int*)  d_in[3];
    const float* sinks   = (const float*)d_in[4];
    const int*   win     = (const int*)  d_in[5];
    float* out = (float*)d_out;

    const size_t wsK_elems = (size_t)NPHYS * 8 * BS_ * D_;   // 4.19M ushorts
    const size_t wsV_elems = (size_t)NPHYS * 8 * 2 * 8192;   // 4.19M ushorts
    const size_t need_bytes = (wsK_elems + wsV_elems) * 2;   // ~16.8 MB

    if (ws_size >= need_bytes) {
        unsigned short* wsK = (unsigned short*)d_ws;
        unsigned short* wsV = wsK + wsK_elems;
        swa_prepass<<<dim3(NPHYS * 8 * 2), dim3(256), 0, stream>>>(kv, wsK, wsV);
        swa_main<<<dim3(B_ * HQ_ * (Q_ / QBLK)), dim3(256), 0, stream>>>(
            q, btab, seqused, sinks, win, wsK, wsV, out);
    } else {
        swa_fallback<<<dim3(B_ * HQ_ * (Q_ / QBLK)), dim3(256), 0, stream>>>(
            q, btab, kv, seqused, sinks, win, out);
    }
}

// Round 4
// 53.111 us; speedup vs baseline: 1.4862x; 1.0517x over previous
//
#include <hip/hip_runtime.h>
#include <hip/hip_bf16.h>

// SWA with sinks: B=2, Q=512, HQ=32, HKV=8 (GQA rep=4), D=128, BS=128,
// NBLK=16, MAXK=2048, WIN=1024 (read dynamically). fp32 in/out, bf16 MFMA.
// R4: shuffle-free common-path softmax (per-lane defer-max check + denom
// folded into PV as ones-row MFMA), T5 setprio around MFMA clusters,
// kh-major XCD mapping so each XCD's ws slice (~2.1MB) is L2-resident.

#define B_    2
#define Q_    512
#define HQ_   32
#define HKV_  8
#define D_    128
#define BS_   128
#define NBLK_ 16
#define NPHYS (B_*NBLK_)
#define QBLK  64
#define KBLK  64
#define PP    72    // P LDS pitch (ushort), 144B rows
#define KVROW (HKV_*D_)   // 1024 floats per key position

typedef __attribute__((ext_vector_type(8))) __bf16 bf16x8;
typedef __attribute__((ext_vector_type(4))) float  f32x4;
typedef __attribute__((ext_vector_type(4))) float  float4v;
typedef __attribute__((ext_vector_type(4))) unsigned int u32x4;
typedef __attribute__((ext_vector_type(2))) unsigned int u32x2;

#if __has_builtin(__builtin_amdgcn_exp2f)
#define EXP2(x) __builtin_amdgcn_exp2f(x)
#else
#define EXP2(x) exp2f(x)
#endif

// Compiler emits v_cvt_pk_bf16_f32 from paired scalar casts (m240).
__device__ __forceinline__ unsigned pk2(float a, float b) {
    union { __bf16 h[2]; unsigned u; } x;
    x.h[0] = (__bf16)a; x.h[1] = (__bf16)b;
    return x.u;
}

__device__ __forceinline__ void gld16(const void* g, void* l) {
    __builtin_amdgcn_global_load_lds(
        (const __attribute__((address_space(1))) void*)g,
        (__attribute__((address_space(3))) void*)l, 16, 0, 0);
}

// ---------------- pre-pass: fp32 KV -> bf16 ws, relayout ----------------
// wsK: [phys][kh][key 128][d 128] bf16, 256B rows XOR-swizzled byte^=(key&15)<<4
// wsV: [phys][kh][tile 2][8192] bf16 fragment-linear (see R3)
// Grid mapping: bid&7 = kh so prepass writes land in the consumer XCD's L2.
__global__ __launch_bounds__(256) void swa_prepass(
    const float* __restrict__ kv,
    unsigned short* __restrict__ wsK,
    unsigned short* __restrict__ wsV)
{
    const int tid  = threadIdx.x;
    const int kh   = blockIdx.x & 7;
    const int rest = blockIdx.x >> 3;
    const int phys = rest >> 1;
    const int part = rest & 1;
    const int pk   = phys * 8 + kh;

    if (part == 0) {
        const int row = tid >> 1;
        const int dh  = (tid & 1) * 64;
        const float* src = kv + ((size_t)(phys * 2 + 0) * BS_ + row) * KVROW + kh * D_ + dh;
        char* dstrow = (char*)(wsK + ((size_t)pk * BS_ + row) * D_);
        const int swz = (row & 15) << 4;
        #pragma unroll
        for (int i = 0; i < 8; ++i) {
            const float4v f0 = *reinterpret_cast<const float4v*>(src + i * 8);
            const float4v f1 = *reinterpret_cast<const float4v*>(src + i * 8 + 4);
            u32x4 p;
            p[0] = pk2(f0[0], f0[1]); p[1] = pk2(f0[2], f0[3]);
            p[2] = pk2(f1[0], f1[1]); p[3] = pk2(f1[2], f1[3]);
            *reinterpret_cast<u32x4*>(dstrow + ((dh * 2 + i * 16) ^ swz)) = p;
        }
    } else {
        const int db  = tid & 31;
        const int kb8 = tid >> 5;
        #pragma unroll
        for (int tile = 0; tile < 2; ++tile) {
            unsigned short* dstt = wsV + ((size_t)pk * 2 + tile) * 8192;
            #pragma unroll
            for (int half = 0; half < 2; ++half) {
                const int kb  = kb8 + half * 8;
                const int k0  = kb * 4;
                const int key = tile * 64 + k0;
                const float* vsrc = kv + ((size_t)(phys * 2 + 1) * BS_ + key) * KVROW + kh * D_ + db * 4;
                const float4v r0 = *reinterpret_cast<const float4v*>(vsrc);
                const float4v r1 = *reinterpret_cast<const float4v*>(vsrc + KVROW);
                const float4v r2 = *reinterpret_cast<const float4v*>(vsrc + 2 * KVROW);
                const float4v r3 = *reinterpret_cast<const float4v*>(vsrc + 3 * KVROW);
                #pragma unroll
                for (int dd = 0; dd < 4; ++dd) {
                    const int d    = db * 4 + dd;
                    const int g    = d >> 4;
                    const int slot = ((kb >> 1) & 3) * 16 + ((d & 15) ^ (g & 7));
                    const int elem = (g * 2 + (k0 >> 5)) * 512 + slot * 8 + (k0 & 7);
                    u32x2 wv;
                    wv[0] = pk2(r0[dd], r1[dd]);
                    wv[1] = pk2(r2[dd], r3[dd]);
                    *reinterpret_cast<u32x2*>(dstt + elem) = wv;
                }
            }
        }
    }
}

// ---------------- main kernel ----------------
__global__ __launch_bounds__(256, 2) void swa_main(
    const float* __restrict__ q,
    const int*   __restrict__ btab,
    const int*   __restrict__ seqused,
    const float* __restrict__ sinks,
    const int*   __restrict__ winp,
    const unsigned short* __restrict__ wsK,
    const unsigned short* __restrict__ wsV,
    float*       __restrict__ out)
{
    __shared__ __align__(16) unsigned short Kb[2][8192];
    __shared__ __align__(16) unsigned short Vb[2][8192];
    __shared__ __align__(16) unsigned short Pl[4][16 * PP];

    const int tid  = threadIdx.x;
    const int lane = tid & 63;
    const int w    = tid >> 6;
    const int l15  = lane & 15;
    const int lhi  = lane >> 4;

    // kh-major block mapping: bid%8 = kh -> same-kh blocks share an XCD L2.
    const int bid   = blockIdx.x;
    const int kh    = bid & 7;
    const int inner = bid >> 3;
    const int qt    = inner & 7;
    const int hr    = (inner >> 3) & 3;
    const int b     = inner >> 5;
    const int h     = kh * 4 + hr;

    const int seq  = seqused[b];
    const int win  = winp[0];
    const int q0   = qt * QBLK;
    const int pos0 = seq - Q_ + q0;

    const int lo  = pos0 - win + 1;
    const int jt0 = (lo < 0 ? 0 : lo) & ~63;
    const int jt1 = (pos0 + QBLK - 1) & ~63;
    const int nt  = ((jt1 - jt0) >> 6) + 1;

    const float SCL2 = 0.08838834764831845f * 1.4426950408889634f;

    // ---- Q fragments ----
    const int    qr    = q0 + w * 16 + l15;
    const size_t qbase = ((size_t)(b * Q_ + qr) * HQ_ + h) * D_;
    bf16x8 qf[4];
    #pragma unroll
    for (int dc = 0; dc < 4; ++dc) {
        const float4v f0 = *reinterpret_cast<const float4v*>(q + qbase + dc * 32 + lhi * 8);
        const float4v f1 = *reinterpret_cast<const float4v*>(q + qbase + dc * 32 + lhi * 8 + 4);
        u32x4 p;
        p[0] = pk2(f0[0] * SCL2, f0[1] * SCL2); p[1] = pk2(f0[2] * SCL2, f0[3] * SCL2);
        p[2] = pk2(f1[0] * SCL2, f1[1] * SCL2); p[3] = pk2(f1[2] * SCL2, f1[3] * SCL2);
        qf[dc] = __builtin_bit_cast(bf16x8, p);
    }

    const bf16x8 ones = __builtin_bit_cast(bf16x8,
        (u32x4){0x3F803F80u, 0x3F803F80u, 0x3F803F80u, 0x3F803F80u});

    const int   pqmin = pos0 + w * 16;
    const int   pqmax = pqmin + 15;
    const int   posq  = pqmin + l15;
    const float sink2 = sinks[h] * 1.4426950408889634f;
    float mrun  = sink2;     // running max (log2 units), row-consistent
    float lsink = 1.0f;      // running 2^(sink2 - mrun)
    f32x4 lacc  = (f32x4){0.f, 0.f, 0.f, 0.f};   // denom via ones-MFMA
    f32x4 o[8];
    #pragma unroll
    for (int g = 0; g < 8; ++g) o[g] = (f32x4){0.f, 0.f, 0.f, 0.f};

    // ---- stage tile 0 ----
    {
        const int blk = btab[b * NBLK_ + (jt0 >> 7)];
        const unsigned short* ks = wsK + ((size_t)(blk * 8 + kh) * BS_ + (jt0 & 127)) * D_;
        const unsigned short* vs = wsV + ((size_t)(blk * 8 + kh) * 2 + ((jt0 >> 6) & 1)) * 8192;
        #pragma unroll
        for (int i = 0; i < 4; ++i)
            gld16(ks + (w * 4 + i) * 512 + lane * 8, &Kb[0][(w * 4 + i) * 512]);
        #pragma unroll
        for (int i = 0; i < 4; ++i)
            gld16(vs + (w * 4 + i) * 512 + lane * 8, &Vb[0][(w * 4 + i) * 512]);
    }
    __syncthreads();

    int cur = 0;
    for (int t = 0; t < nt; ++t) {
        const int jt = jt0 + t * KBLK;

        // ---- prefetch next tile into other buffer ----
        if (t + 1 < nt) {
            const int jn  = jt + KBLK;
            const int blk = btab[b * NBLK_ + (jn >> 7)];
            const unsigned short* ks = wsK + ((size_t)(blk * 8 + kh) * BS_ + (jn & 127)) * D_;
            const unsigned short* vs = wsV + ((size_t)(blk * 8 + kh) * 2 + ((jn >> 6) & 1)) * 8192;
            const int nb = cur ^ 1;
            #pragma unroll
            for (int i = 0; i < 4; ++i)
                gld16(ks + (w * 4 + i) * 512 + lane * 8, &Kb[nb][(w * 4 + i) * 512]);
            #pragma unroll
            for (int i = 0; i < 4; ++i)
                gld16(vs + (w * 4 + i) * 512 + lane * 8, &Vb[nb][(w * 4 + i) * 512]);
        }

        // ---- compute (skip if fully masked for this wave) ----
        if (jt <= pqmax && jt + KBLK - 1 > pqmin - win) {
            const bool edge = (jt + KBLK - 1 > pqmin) || (jt <= pqmax - win);

            f32x4 sacc[4];
            #pragma unroll
            for (int g = 0; g < 4; ++g) sacc[g] = (f32x4){0.f, 0.f, 0.f, 0.f};
            __builtin_amdgcn_s_setprio(1);
            #pragma unroll
            for (int g = 0; g < 4; ++g) {
                const char* krow = (const char*)&Kb[cur][0] + (g * 16 + l15) * 256;
                const int   swz  = (l15 << 4);
                #pragma unroll
                for (int dc = 0; dc < 4; ++dc) {
                    const bf16x8 a = *reinterpret_cast<const bf16x8*>(
                        krow + ((dc * 64 + lhi * 16) ^ swz));
                    sacc[g] = __builtin_amdgcn_mfma_f32_16x16x32_bf16(a, qf[dc], sacc[g], 0, 0, 0);
                }
            }
            __builtin_amdgcn_s_setprio(0);

            // ---- masking + per-lane local max (NO cross-lane in common path) ----
            float sv[16];
            float mloc = -3e38f;
            if (edge) {
                #pragma unroll
                for (int g = 0; g < 4; ++g) {
                    #pragma unroll
                    for (int i = 0; i < 4; ++i) {
                        const int  kglob = jt + g * 16 + lhi * 4 + i;
                        const bool ok = (kglob <= posq) && (kglob > posq - win);
                        const float s = ok ? sacc[g][i] : -1e30f;
                        sv[g * 4 + i] = s;
                        mloc = fmaxf(mloc, s);
                    }
                }
            } else {
                #pragma unroll
                for (int g = 0; g < 4; ++g) {
                    #pragma unroll
                    for (int i = 0; i < 4; ++i) {
                        sv[g * 4 + i] = sacc[g][i];
                        mloc = fmaxf(mloc, sacc[g][i]);
                    }
                }
            }

            // T13 defer-rescale: wave-collective check, no shuffles needed.
            // (per-lane partial <= thr for all lanes  <=>  row max <= thr)
            if (!__all(mloc <= mrun + 8.0f)) {
                float mrow = fmaxf(mloc, __shfl_xor(mloc, 16));
                mrow = fmaxf(mrow, __shfl_xor(mrow, 32));
                const float mnew  = fmaxf(mrun, mrow);
                const float alpha = EXP2(mrun - mnew);
                lsink *= alpha;
                lacc  *= alpha;
                #pragma unroll
                for (int g = 0; g < 8; ++g) o[g] *= alpha;
                mrun = mnew;
            }

            unsigned pw[8];
            #pragma unroll
            for (int t2 = 0; t2 < 8; ++t2) {
                const float p0 = EXP2(sv[2 * t2]     - mrun);
                const float p1 = EXP2(sv[2 * t2 + 1] - mrun);
                pw[t2] = pk2(p0, p1);
            }

            #pragma unroll
            for (int g = 0; g < 4; ++g) {
                u32x2 wv; wv[0] = pw[2 * g]; wv[1] = pw[2 * g + 1];
                *reinterpret_cast<u32x2*>(&Pl[w][l15 * PP + g * 16 + lhi * 4]) = wv;
            }

            // ---- O^T += V^T·P ; denom += ones·P (8+1 d-frags x 2 k-chunks) ----
            __builtin_amdgcn_s_setprio(1);
            #pragma unroll
            for (int kc = 0; kc < 2; ++kc) {
                const bf16x8 pf = *reinterpret_cast<const bf16x8*>(
                    &Pl[w][l15 * PP + kc * 32 + lhi * 8]);
                lacc = __builtin_amdgcn_mfma_f32_16x16x32_bf16(ones, pf, lacc, 0, 0, 0);
                #pragma unroll
                for (int g = 0; g < 8; ++g) {
                    const bf16x8 vf = *reinterpret_cast<const bf16x8*>(
                        &Vb[cur][(g * 2 + kc) * 512 + (lhi * 16 + (l15 ^ (g & 7))) * 8]);
                    o[g] = __builtin_amdgcn_mfma_f32_16x16x32_bf16(vf, pf, o[g], 0, 0, 0);
                }
            }
            __builtin_amdgcn_s_setprio(0);
        }

        __syncthreads();   // drains vmcnt (prefetch done) + protects buffers
        cur ^= 1;
    }

    // ---- epilogue: out = O / (sum_p + sink_term) ----
    const float  inv   = 1.0f / (lacc[0] + lsink);
    const size_t obase = ((size_t)(b * Q_ + qr) * HQ_ + h) * D_;
    #pragma unroll
    for (int g = 0; g < 8; ++g) {
        float4v v;
        v[0] = o[g][0] * inv; v[1] = o[g][1] * inv;
        v[2] = o[g][2] * inv; v[3] = o[g][3] * inv;
        *reinterpret_cast<float4v*>(out + obase + g * 16 + lhi * 4) = v;
    }
}

// ---------------- fallback (R2 kernel, used if ws too small) ----------------
__global__ __launch_bounds__(256, 2) void swa_fallback(
    const float* __restrict__ q,
    const int*   __restrict__ btab,
    const float* __restrict__ kv,
    const int*   __restrict__ seqused,
    const float* __restrict__ sinks,
    const int*   __restrict__ winp,
    float*       __restrict__ out)
{
    __shared__ __align__(16) unsigned short Klds[64 * 128];
    __shared__ __align__(16) unsigned short Vlds[64 * 128];
    __shared__ __align__(16) unsigned short Plds[4][16 * PP];

    const int tid  = threadIdx.x;
    const int lane = tid & 63;
    const int w    = tid >> 6;
    const int l15  = lane & 15;
    const int lhi  = lane >> 4;

    const int bid = blockIdx.x;
    const int qt  = bid & 7;
    const int h   = (bid >> 3) & 31;
    const int b   = bid >> 8;
    const int kh  = h >> 2;

    const int seq  = seqused[b];
    const int win  = winp[0];
    const int q0   = qt * QBLK;
    const int pos0 = seq - Q_ + q0;

    const int lo  = pos0 - win + 1;
    const int jt0 = (lo < 0 ? 0 : lo) & ~63;
    const int jt1 = (pos0 + QBLK - 1) & ~63;

    const float SCL2 = 0.08838834764831845f * 1.4426950408889634f;

    const int    qr    = q0 + w * 16 + l15;
    const size_t qbase = ((size_t)(b * Q_ + qr) * HQ_ + h) * D_;
    bf16x8 qf[4];
    #pragma unroll
    for (int dc = 0; dc < 4; ++dc) {
        const float4v f0 = *reinterpret_cast<const float4v*>(q + qbase + dc * 32 + lhi * 8);
        const float4v f1 = *reinterpret_cast<const float4v*>(q + qbase + dc * 32 + lhi * 8 + 4);
        u32x4 p;
        p[0] = pk2(f0[0] * SCL2, f0[1] * SCL2); p[1] = pk2(f0[2] * SCL2, f0[3] * SCL2);
        p[2] = pk2(f1[0] * SCL2, f1[1] * SCL2); p[3] = pk2(f1[2] * SCL2, f1[3] * SCL2);
        qf[dc] = __builtin_bit_cast(bf16x8, p);
    }

    const int   pqmin = pos0 + w * 16;
    const int   pqmax = pqmin + 15;
    const int   posq  = pqmin + l15;
    const float sink2 = sinks[h] * 1.4426950408889634f;
    float mrun = sink2;
    float lrun = 1.0f;
    f32x4 o[8];
    #pragma unroll
    for (int g = 0; g < 8; ++g) o[g] = (f32x4){0.f, 0.f, 0.f, 0.f};

    for (int jt = jt0; jt <= jt1; jt += KBLK) {
        const int    blk    = btab[b * NBLK_ + (jt >> 7)];
        const size_t kgbase = (size_t)blk * (2 * BS_ * KVROW) + (size_t)(jt & 127) * KVROW + kh * D_;
        const size_t vgbase = kgbase + (size_t)BS_ * KVROW;

        __syncthreads();
        {
            const int kl = tid >> 2;
            const int cb = (tid & 3) * 64;
            const float* src = kv + kgbase + (size_t)kl * KVROW + (tid & 3) * 32;
            char* dst = (char*)Klds + kl * 256;
            #pragma unroll
            for (int i = 0; i < 4; ++i) {
                const float4v f0 = *reinterpret_cast<const float4v*>(src + i * 8);
                const float4v f1 = *reinterpret_cast<const float4v*>(src + i * 8 + 4);
                u32x4 p;
                p[0] = pk2(f0[0], f0[1]); p[1] = pk2(f0[2], f0[3]);
                p[2] = pk2(f1[0], f1[1]); p[3] = pk2(f1[2], f1[3]);
                *reinterpret_cast<u32x4*>(dst + ((cb + i * 16) ^ ((kl & 15) << 4))) = p;
            }
        }
        {
            const int db = tid & 31;
            #pragma unroll
            for (int half = 0; half < 2; ++half) {
                const int kb = (tid >> 5) + half * 8;
                const int k0 = kb * 4;
                const float* vsrc = kv + vgbase + (size_t)k0 * KVROW + db * 4;
                const float4v r0 = *reinterpret_cast<const float4v*>(vsrc);
                const float4v r1 = *reinterpret_cast<const float4v*>(vsrc + KVROW);
                const float4v r2 = *reinterpret_cast<const float4v*>(vsrc + 2 * KVROW);
                const float4v r3 = *reinterpret_cast<const float4v*>(vsrc + 3 * KVROW);
                #pragma unroll
                for (int dd = 0; dd < 4; ++dd) {
                    const int d    = db * 4 + dd;
                    const int g    = d >> 4;
                    const int slot = ((kb >> 1) & 3) * 16 + ((d & 15) ^ (g & 7));
                    const int elem = (g * 2 + (k0 >> 5)) * 512 + slot * 8 + (k0 & 7);
                    u32x2 wv;
                    wv[0] = pk2(r0[dd], r1[dd]);
                    wv[1] = pk2(r2[dd], r3[dd]);
                    *reinterpret_cast<u32x2*>(&Vlds[elem]) = wv;
                }
            }
        }
        __syncthreads();

        if (jt > pqmax || jt + KBLK - 1 <= pqmin - win) continue;
        const bool edge = (jt + KBLK - 1 > pqmin) || (jt <= pqmax - win);

        f32x4 sacc[4];
        #pragma unroll
        for (int g = 0; g < 4; ++g) sacc[g] = (f32x4){0.f, 0.f, 0.f, 0.f};
        #pragma unroll
        for (int g = 0; g < 4; ++g) {
            const char* krow = (const char*)Klds + (g * 16 + l15) * 256;
            const int   swz  = (l15 << 4);
            #pragma unroll
            for (int dc = 0; dc < 4; ++dc) {
                const bf16x8 a = *reinterpret_cast<const bf16x8*>(
                    krow + ((dc * 64 + lhi * 16) ^ swz));
                sacc[g] = __builtin_amdgcn_mfma_f32_16x16x32_bf16(a, qf[dc], sacc[g], 0, 0, 0);
            }
        }

        float sv[16];
        float mloc = -3e38f;
        if (edge) {
            #pragma unroll
            for (int g = 0; g < 4; ++g) {
                #pragma unroll
                for (int i = 0; i < 4; ++i) {
                    const int  kglob = jt + g * 16 + lhi * 4 + i;
                    const bool ok = (kglob <= posq) && (kglob > posq - win);
                    const float s = ok ? sacc[g][i] : -1e30f;
                    sv[g * 4 + i] = s;
                    mloc = fmaxf(mloc, s);
                }
            }
        } else {
            #pragma unroll
            for (int g = 0; g < 4; ++g) {
                #pragma unroll
                for (int i = 0; i < 4; ++i) {
                    sv[g * 4 + i] = sacc[g][i];
                    mloc = fmaxf(mloc, sacc[g][i]);
                }
            }
        }
        mloc = fmaxf(mloc, __shfl_xor(mloc, 16));
        mloc = fmaxf(mloc, __shfl_xor(mloc, 32));

        if (!__all(mloc <= mrun + 8.0f)) {
            const float mnew  = fmaxf(mrun, mloc);
            const float alpha = EXP2(mrun - mnew);
            lrun *= alpha;
            #pragma unroll
            for (int g = 0; g < 8; ++g) o[g] *= alpha;
            mrun = mnew;
        }

        float ps = 0.f;
        unsigned pw[8];
        #pragma unroll
        for (int t = 0; t < 8; ++t) {
            const float p0 = EXP2(sv[2 * t]     - mrun);
            const float p1 = EXP2(sv[2 * t + 1] - mrun);
            ps += p0 + p1;
            pw[t] = pk2(p0, p1);
        }
        ps += __shfl_xor(ps, 16);
        ps += __shfl_xor(ps, 32);
        lrun += ps;

        #pragma unroll
        for (int g = 0; g < 4; ++g) {
            u32x2 wv; wv[0] = pw[2 * g]; wv[1] = pw[2 * g + 1];
            *reinterpret_cast<u32x2*>(&Plds[w][l15 * PP + g * 16 + lhi * 4]) = wv;
        }

        #pragma unroll
        for (int kc = 0; kc < 2; ++kc) {
            const bf16x8 pf = *reinterpret_cast<const bf16x8*>(
                &Plds[w][l15 * PP + kc * 32 + lhi * 8]);
            #pragma unroll
            for (int g = 0; g < 8; ++g) {
                const bf16x8 vf = *reinterpret_cast<const bf16x8*>(
                    &Vlds[(g * 2 + kc) * 512 + (lhi * 16 + (l15 ^ (g & 7))) * 8]);
                o[g] = __builtin_amdgcn_mfma_f32_16x16x32_bf16(vf, pf, o[g], 0, 0, 0);
            }
        }
    }

    const float  inv   = 1.0f / lrun;
    const size_t obase = ((size_t)(b * Q_ + qr) * HQ_ + h) * D_;
    #pragma unroll
    for (int g = 0; g < 8; ++g) {
        float4v v;
        v[0] = o[g][0] * inv; v[1] = o[g][1] * inv;
        v[2] = o[g][2] * inv; v[3] = o[g][3] * inv;
        *reinterpret_cast<float4v*>(out + obase + g * 16 + lhi * 4) = v;
    }
}

extern "C" void kernel_launch(void* const* d_in, const int* in_sizes, int n_in,
                              void* d_out, int out_size, void* d_ws, size_t ws_size,
                              hipStream_t stream) {
    const float* q       = (const float*)d_in[0];
    const int*   btab    = (const int*)  d_in[1];
    const float* kv      = (const float*)d_in[2];
    const int*   seqused = (const int*)  d_in[3];
    const float* sinks   = (const float*)d_in[4];
    const int*   win     = (const int*)  d_in[5];
    float* out = (float*)d_out;

    const size_t wsK_elems = (size_t)NPHYS * 8 * BS_ * D_;   // 4.19M ushorts
    const size_t wsV_elems = (size_t)NPHYS * 8 * 2 * 8192;   // 4.19M ushorts
    const size_t need_bytes = (wsK_elems + wsV_elems) * 2;   // ~16.8 MB

    if (ws_size >= need_bytes) {
        unsigned short* wsK = (unsigned short*)d_ws;
        unsigned short* wsV = wsK + wsK_elems;
        swa_prepass<<<dim3(NPHYS * 8 * 2), dim3(256), 0, stream>>>(kv, wsK, wsV);
        swa_main<<<dim3(B_ * HQ_ * (Q_ / QBLK)), dim3(256), 0, stream>>>(
            q, btab, seqused, sinks, win, wsK, wsV, out);
    } else {
        swa_fallback<<<dim3(B_ * HQ_ * (Q_ / QBLK)), dim3(256), 0, stream>>>(
            q, btab, kv, seqused, sinks, win, out);
    }
}